// Round 21
// baseline (281.795 us; speedup 1.0000x reference)
//
#include <hip/hip_runtime.h>
#include <math.h>

typedef __bf16 bf16x8 __attribute__((ext_vector_type(8)));
typedef __bf16 bf16x4 __attribute__((ext_vector_type(4)));
typedef float  f32x4  __attribute__((ext_vector_type(4)));
typedef unsigned int u32x4 __attribute__((ext_vector_type(4)));

#define B_   2
#define N_   4096
#define D_   512
#define H_   8
#define FF_  2048
#define BN_  (B_*N_)
static constexpr float SCALE_ = 0.04419417382415922f;  // 512^-0.5
static constexpr float LOG2E_ = 1.44269504088896341f;
static constexpr float SCALE_L2E_ = SCALE_ * LOG2E_;   // fold log2e into Q scale

#define GLOAD_LDS16(g, l) __builtin_amdgcn_global_load_lds( \
    (const __attribute__((address_space(1))) void*)(g),     \
    (__attribute__((address_space(3))) void*)(l), 16, 0, 0)

// ---------------- fused prep: ln1 (blocks 0..4095, 2 rows each) + all four ----------------
// weight transposes f32[R][C] -> bf16[C][R] (blocks 4096..7167, one 32x32 tile).
__global__ __launch_bounds__(256)
void prep_kernel(const float* __restrict__ x, const float* __restrict__ ln1_w,
                 const float* __restrict__ ln1_b, __bf16* __restrict__ hbuf,
                 const float* __restrict__ qkv_w,  __bf16* __restrict__ qkv_wt,
                 const float* __restrict__ proj_w, __bf16* __restrict__ proj_wt,
                 const float* __restrict__ fc1_w,  __bf16* __restrict__ fc1_wt,
                 const float* __restrict__ fc2_w,  __bf16* __restrict__ fc2_wt) {
    const int bid = blockIdx.x, tid = threadIdx.x;
    __shared__ float tile[32][33];
    __shared__ float ps[4][2];
    if (bid < 4096) {
        // ---- LayerNorm: two rows per block (group = tid>>7 of 128 threads) ----
        const int grp = tid >> 7, t = tid & 127;
        const int row = bid * 2 + grp;
        const float4 v = *(const float4*)&x[(size_t)row * 512 + t * 4];
        float s  = v.x + v.y + v.z + v.w;
        float sq = v.x*v.x + v.y*v.y + v.z*v.z + v.w*v.w;
#pragma unroll
        for (int mk = 1; mk < 64; mk <<= 1) { s += __shfl_xor(s, mk); sq += __shfl_xor(sq, mk); }
        if ((t & 63) == 0) { ps[tid >> 6][0] = s; ps[tid >> 6][1] = sq; }
        __syncthreads();
        s  = ps[grp * 2][0] + ps[grp * 2 + 1][0];
        sq = ps[grp * 2][1] + ps[grp * 2 + 1][1];
        const float mu  = s * (1.0f / 512.0f);
        const float var = sq * (1.0f / 512.0f) - mu * mu;
        const float rs  = rsqrtf(var + 1e-5f);
        const float4 wv = *(const float4*)&ln1_w[t * 4];
        const float4 bv = *(const float4*)&ln1_b[t * 4];
        bf16x4 o;
        o[0] = (__bf16)((v.x - mu) * rs * wv.x + bv.x);
        o[1] = (__bf16)((v.y - mu) * rs * wv.y + bv.y);
        o[2] = (__bf16)((v.z - mu) * rs * wv.z + bv.z);
        o[3] = (__bf16)((v.w - mu) * rs * wv.w + bv.w);
        *(bf16x4*)&hbuf[(size_t)row * 512 + t * 4] = o;
    } else {
        // ---- weight transpose tiles ----
        int idx = bid - 4096;
        const float* in; __bf16* out; int C, R, txc, tyr;
        if (idx < 768)       { in = qkv_w;  out = qkv_wt;  R = 512;  C = 1536;
                               txc = idx % 48; tyr = idx / 48; }
        else if (idx < 1024) { idx -= 768;  in = proj_w; out = proj_wt; R = 512;  C = 512;
                               txc = idx % 16; tyr = idx / 16; }
        else if (idx < 2048) { idx -= 1024; in = fc1_w;  out = fc1_wt;  R = 512;  C = 2048;
                               txc = idx % 64; tyr = idx / 64; }
        else                 { idx -= 2048; in = fc2_w;  out = fc2_wt;  R = 2048; C = 512;
                               txc = idx % 16; tyr = idx / 16; }
        const int c0 = txc * 32, r0 = tyr * 32;
        const int tx = tid & 31, ty = tid >> 5;   // (32,8)
#pragma unroll
        for (int i = 0; i < 4; ++i)
            tile[ty + 8*i][tx] = in[(size_t)(r0 + ty + 8*i) * C + c0 + tx];
        __syncthreads();
#pragma unroll
        for (int i = 0; i < 4; ++i)
            out[(size_t)(c0 + ty + 8*i) * R + r0 + tx] = (__bf16)tile[tx][ty + 8*i];
    }
}

// ---------------- LayerNorm f32 -> bf16, one row (512) per block of 128 ----------------
__global__ __launch_bounds__(128)
void ln_kernel(const float* __restrict__ x, const float* __restrict__ w,
               const float* __restrict__ b, __bf16* __restrict__ out) {
    const int row = blockIdx.x, t = threadIdx.x;
    const float4 v = *(const float4*)&x[(size_t)row * 512 + t * 4];
    float s  = v.x + v.y + v.z + v.w;
    float sq = v.x*v.x + v.y*v.y + v.z*v.z + v.w*v.w;
#pragma unroll
    for (int mk = 1; mk < 64; mk <<= 1) { s += __shfl_xor(s, mk); sq += __shfl_xor(sq, mk); }
    __shared__ float ps[2][2];
    if ((t & 63) == 0) { ps[t >> 6][0] = s; ps[t >> 6][1] = sq; }
    __syncthreads();
    s = ps[0][0] + ps[1][0]; sq = ps[0][1] + ps[1][1];
    const float mu  = s * (1.0f / 512.0f);
    const float var = sq * (1.0f / 512.0f) - mu * mu;
    const float rs  = rsqrtf(var + 1e-5f);
    const float4 wv = *(const float4*)&w[t * 4];
    const float4 bv = *(const float4*)&b[t * 4];
    bf16x4 o;
    o[0] = (__bf16)((v.x - mu) * rs * wv.x + bv.x);
    o[1] = (__bf16)((v.y - mu) * rs * wv.y + bv.y);
    o[2] = (__bf16)((v.z - mu) * rs * wv.z + bv.z);
    o[3] = (__bf16)((v.w - mu) * rs * wv.w + bv.w);
    *(bf16x4*)&out[(size_t)row * 512 + t * 4] = o;
}

// ---------------- bf16 GEMM, C = A[M,K] * Bt[N,K]^T, fused epilogues ----------------
// EPI 0: +bias -> bf16 | EPI 1: +bias, exact gelu -> bf16 | EPI 2: +bias +resid(f32) -> f32
// Epilogue is LDS-transposed + vectorized (r14 win: 64 scalar VMEM -> 8/16 vector).
template<int EPI, int BNT, bool DBUF>
__global__ __launch_bounds__(256, 4)
void gemm_bt(const __bf16* __restrict__ A, const __bf16* __restrict__ Bt,
             const float* __restrict__ bias, const float* __restrict__ resid,
             __bf16* __restrict__ outb, float* __restrict__ outf,
             int M, int N, int K) {
    constexpr int NI = BNT / 32;                  // n-frags per wave (4 or 2)
    constexpr int NB = DBUF ? 2 : 1;
    __shared__ __align__(16) __bf16 As[NB][128 * 64];
    __shared__ __align__(16) __bf16 Bs[NB][BNT * 64];
    const int tid = threadIdx.x;
    const int w = tid >> 6, l = tid & 63;
    const int g = l >> 4, c = l & 15;
    const int m0 = blockIdx.y * 128, n0 = blockIdx.x * BNT;
    const int wm = (w >> 1) * 64, wn = (w & 1) * (BNT / 2);
    f32x4 acc[4][NI] = {};

    auto stage = [&](int kt, int buf) {
#pragma unroll
        for (int i = 0; i < 4; ++i) {             // A tile: 128x64
            const int cb = (i * 4 + w) * 64;      // wave-uniform chunk base
            const int chunk = cb + l;
            const int row = chunk >> 3, c8 = chunk & 7;
            GLOAD_LDS16(A + (size_t)(m0 + row) * K + kt + c8 * 8, As[buf] + cb * 8);
        }
#pragma unroll
        for (int i = 0; i < BNT / 32; ++i) {      // B tile: BNTx64
            const int cb = (i * 4 + w) * 64;
            const int chunk = cb + l;
            const int row = chunk >> 3, c8 = chunk & 7;
            GLOAD_LDS16(Bt + (size_t)(n0 + row) * K + kt + c8 * 8, Bs[buf] + cb * 8);
        }
    };
    auto compute = [&](int buf) {
#pragma unroll
        for (int kk = 0; kk < 2; ++kk) {
            bf16x8 av[4], bv[NI];
#pragma unroll
            for (int mi = 0; mi < 4; ++mi)
                av[mi] = *(const bf16x8*)&As[buf][(wm + mi * 16 + c) * 64 + kk * 32 + g * 8];
#pragma unroll
            for (int ni = 0; ni < NI; ++ni)
                bv[ni] = *(const bf16x8*)&Bs[buf][(wn + ni * 16 + c) * 64 + kk * 32 + g * 8];
#pragma unroll
            for (int mi = 0; mi < 4; ++mi)
#pragma unroll
                for (int ni = 0; ni < NI; ++ni)
                    acc[mi][ni] = __builtin_amdgcn_mfma_f32_16x16x32_bf16(
                        av[mi], bv[ni], acc[mi][ni], 0, 0, 0);
        }
    };

    if constexpr (DBUF) {
        stage(0, 0);
        const int T = K / 64;
        for (int t = 0; t < T; ++t) {
            const int cur = t & 1;
            __syncthreads();
            if (t + 1 < T) stage((t + 1) * 64, cur ^ 1);
            compute(cur);
        }
    } else {
        for (int kt = 0; kt < K; kt += 64) {
            __syncthreads();
            stage(kt, 0);
            __syncthreads();
            compute(0);
        }
    }

    // ---- vectorized epilogue (wave-local LDS transpose) ----
    __syncthreads();   // all waves done reading As/Bs before we overwrite As
    if constexpr (EPI == 2) {
        // f32 path: per-wave [16][NI*16 + 4] f32 patch in As
        constexpr int LDW = NI * 16 + 4;
        float* ep = (float*)&As[0][0] + w * (16 * LDW);
#pragma unroll
        for (int mi = 0; mi < 4; ++mi) {
#pragma unroll
            for (int ni = 0; ni < NI; ++ni)
#pragma unroll
                for (int r = 0; r < 4; ++r)
                    ep[(g * 4 + r) * LDW + ni * 16 + c] =
                        acc[mi][ni][r] + bias[n0 + wn + ni * 16 + c];
#pragma unroll
            for (int rnd = 0; rnd < NI; ++rnd) {          // 16*NI*16 f32 / (64*4)
                const int idx = rnd * 64 + l;
                const int rr = idx >> 3, cc = idx & 7;
                const f32x4 vv = *(const f32x4*)&ep[rr * LDW + cc * 4];
                const size_t oidx = (size_t)(m0 + wm + mi * 16 + rr) * N + n0 + wn + cc * 4;
                const f32x4 rv = *(const f32x4*)&resid[oidx];
                *(f32x4*)&outf[oidx] = vv + rv;
            }
        }
    } else {
        // bf16 path: per-wave [16][NI*16 + 8] bf16 patch in As
        constexpr int LDW = NI * 16 + 8;
        __bf16* ep = &As[0][0] + w * (16 * LDW);
#pragma unroll
        for (int mi = 0; mi < 4; ++mi) {
#pragma unroll
            for (int ni = 0; ni < NI; ++ni)
#pragma unroll
                for (int r = 0; r < 4; ++r) {
                    float v = acc[mi][ni][r] + bias[n0 + wn + ni * 16 + c];
                    if constexpr (EPI == 1)
                        v = 0.5f * v * (1.0f + erff(v * 0.70710678118654752f));
                    ep[(g * 4 + r) * LDW + ni * 16 + c] = (__bf16)v;
                }
#pragma unroll
            for (int rnd = 0; rnd < NI / 2; ++rnd) {      // 16*NI*16 bf16 / (64*8)
                const int idx = rnd * 64 + l;
                const int rr = idx >> 3, cc = idx & 7;
                const bf16x8 vv = *(const bf16x8*)&ep[rr * LDW + cc * 8];
                const size_t oidx = (size_t)(m0 + wm + mi * 16 + rr) * N + n0 + wn + cc * 8;
                *(bf16x8*)&outb[oidx] = vv;
            }
        }
    }
}

// ---------------- flash attention: 8 waves, ni-split key halves (r21) ----------------
// r20 structure + dist LDS round-trip DELETED: the dist read pattern is exactly
// lane-private ((row,4-col chunk) <-> (wq,c,hn,nii,g) bijection), so dist loads
// go DIRECTLY to registers (4x f32x4/lane), prefetched at B2 with a
// full-iteration window, pinned by sched_barrier fences (r16 proved reg-held
// dist loads persist). Deletes 4 gload_lds + 4 ds_read_b128 per thread-iter
// and lightens B2's lgkm drain. SCs (32KB LDS) remains ONLY as combine scratch.
__global__ __launch_bounds__(512, 4)
void attn_kernel(const __bf16* __restrict__ qkv, const float* __restrict__ dist,
                 const float* __restrict__ gamma, __bf16* __restrict__ outp) {
    __shared__ __align__(16) __bf16 Ks [64 * 64];      // K tile, linear + XOR swizzle
    __shared__ __align__(16) __bf16 Vts[64][72];       // V transposed, k XOR-swizzled
    __shared__ __align__(16) float  SCs[128 * 64];     // combine scratch only
    const int tid = threadIdx.x;
    const int w = tid >> 6, l = tid & 63;
    const int g = l >> 4, c = l & 15;
    const int wq = w & 3, hn = w >> 2;              // q-row group, key-half
    const int qt = blockIdx.x, h = blockIdx.y;
    const int b = blockIdx.z;
    const float gbl = gamma[b] * LOG2E_;
    const size_t tok0 = (size_t)b * N_;
    const int qrow = 16 * wq + c;                   // lane's local q row (group 0)
    const int wub = tid & 448;                      // w*64, wave-uniform lds chunk base
    const int srow = tid >> 3;                      // staging row (0..63), K/V
    const int sd0  = (tid & 7) * 8;                 // staging d-offset
    const int cswz = ((tid & 7) ^ (srow & 7)) * 8;  // K source pre-swizzle col
    const int swz  = (c & 7) << 3;                  // LDS read swizzle (bf16)

    // Q fragments for both t-groups, pre-scaled by SCALE*log2e
    bf16x8 qf[2][2];
#pragma unroll
    for (int t = 0; t < 2; ++t) {
        const size_t qbase = (tok0 + qt * 128 + 64 * t + qrow) * 1536 + h * 64;
#pragma unroll
        for (int kk = 0; kk < 2; ++kk) {
            const bf16x8 qv = *(const bf16x8*)&qkv[qbase + kk * 32 + g * 8];
#pragma unroll
            for (int j = 0; j < 8; ++j) qf[t][kk][j] = (__bf16)((float)qv[j] * SCALE_L2E_);
        }
    }
    bf16x8 ones;
#pragma unroll
    for (int j = 0; j < 8; ++j) ones[j] = (__bf16)1.0f;

    f32x4 acc[2][4] = {};   // key-half partial: Onum[q=64t+qrow][d=16di+4g+r]
    f32x4 accl[2] = {};     // key-half partial softmax denominator
    bf16x8 vreg;
    f32x4 dreg[2][2];       // dist regs [nii][t-row]; lane-private chunks

    // running global pointers (strength-reduced: advance by constant stride)
    const size_t kvstep = (size_t)64 * 1536;
    const __bf16* gk = qkv + 512  + (tok0 + srow) * 1536 + h * 64 + cswz;
    const __bf16* gv = qkv + 1024 + (tok0 + srow) * 1536 + h * 64 + sd0;
    // dist direct-to-register: this lane owns rows {qrow, 64+qrow},
    // cols {32hn+4g, 32hn+16+4g} (4 f32 each) of every kt-tile.
    const float* gdl = dist + (size_t)(qt * 128 + qrow) * N_ + 32 * hn + 4 * g;

    auto issue_k = [&]() {
        GLOAD_LDS16(gk, Ks + wub * 8);
        gk += kvstep;
    };
    auto issue_v = [&]() {
        vreg = *(const bf16x8*)gv;
        gv += kvstep;
    };
    auto load_dreg = [&]() {    // 4x f32x4 plain loads -> dreg (held in VGPRs)
        dreg[0][0] = *(const f32x4*)gdl;
        dreg[1][0] = *(const f32x4*)(gdl + 16);
        dreg[0][1] = *(const f32x4*)(gdl + (size_t)64 * N_);
        dreg[1][1] = *(const f32x4*)(gdl + (size_t)64 * N_ + 16);
        gdl += 64;
    };
    auto write_vts = [&]() {    // scalar transpose: vreg -> Vts
        const int kp = srow ^ sd0;   // sd0 = (sd0>>3)<<3 here
#pragma unroll
        for (int j = 0; j < 8; ++j) Vts[sd0 + j][kp] = vreg[j];
    };

    const int ktend = N_ / 64;                      // 64 tiles, all keys
    issue_k();
    issue_v();
    load_dreg();

    for (int kt = 0; kt < ktend; ++kt) {
        __syncthreads();     // B1: full drain -- K/V(kt) landed, PV(kt-1) done
        write_vts();
        if (kt + 1 < ktend) issue_v();   // vreg dead after write_vts
        __builtin_amdgcn_sched_barrier(0);

        // consume dreg(kt) -> Cin; hoist kf (the ONLY LDS reads this iter)
        f32x4 cin0[2], cin1[2];          // [nii]: rows qrow, 64+qrow
        bf16x8 kf[2][2];                 // [nii][kk]
#pragma unroll
        for (int nii = 0; nii < 2; ++nii) {
            const int ni = 2 * hn + nii;
#pragma unroll
            for (int r = 0; r < 4; ++r) {
                cin0[nii][r] = -gbl * dreg[nii][0][r];
                cin1[nii][r] = -gbl * dreg[nii][1][r];
            }
#pragma unroll
            for (int kk = 0; kk < 2; ++kk)
                kf[nii][kk] = *(const bf16x8*)
                    &Ks[((16 * ni + c) << 6) + ((kk * 32 + g * 8) ^ swz)];
        }
        __builtin_amdgcn_sched_barrier(0);
        // B2: all kf reads done; own Vts writes drained + visible. Ks free.
        asm volatile("s_waitcnt lgkmcnt(0)\n\ts_barrier" ::: "memory");
        __builtin_amdgcn_sched_barrier(0);
        if (kt + 1 < ktend) {    // prefetches fly across the whole iteration
            issue_k();
            load_dreg();         // dist(kt+1) -> regs (pinned here by fences)
        }
        __builtin_amdgcn_sched_barrier(0);

        // QK^T from registers, Cin = -gbl*dd preloaded
        uint32_t W[2][2][2];
#pragma unroll
        for (int nii = 0; nii < 2; ++nii) {
            f32x4 s0 = cin0[nii], s1 = cin1[nii];
            __builtin_amdgcn_s_setprio(1);
#pragma unroll
            for (int kk = 0; kk < 2; ++kk) {
                s0 = __builtin_amdgcn_mfma_f32_16x16x32_bf16(kf[nii][kk], qf[0][kk], s0, 0, 0, 0);
                s1 = __builtin_amdgcn_mfma_f32_16x16x32_bf16(kf[nii][kk], qf[1][kk], s1, 0, 0, 0);
            }
            __builtin_amdgcn_s_setprio(0);
#pragma unroll
            for (int t = 0; t < 2; ++t) {
                const f32x4 sv = (t == 0) ? s0 : s1;
                float pv0, pv1, pv2, pv3;
                pv0 = __builtin_amdgcn_exp2f(sv[0]);
                pv1 = __builtin_amdgcn_exp2f(sv[1]);
                pv2 = __builtin_amdgcn_exp2f(sv[2]);
                pv3 = __builtin_amdgcn_exp2f(sv[3]);
                asm("v_cvt_pk_bf16_f32 %0, %1, %2" : "=v"(W[t][nii][0]) : "v"(pv0), "v"(pv1));
                asm("v_cvt_pk_bf16_f32 %0, %1, %2" : "=v"(W[t][nii][1]) : "v"(pv2), "v"(pv3));
            }
        }
        // P-word exchange within the half: (W[nii=0],W[nii=1]) -> pa[kk=hn]
        bf16x8 pa[2];
#pragma unroll
        for (int t = 0; t < 2; ++t) {
#pragma unroll
            for (int p = 0; p < 2; ++p) {
                asm("v_permlane32_swap_b32 %0, %1"
                    : "+v"(W[t][0][p]), "+v"(W[t][1][p]));
                asm("v_permlane16_swap_b32 %0, %1"
                    : "+v"(W[t][0][p]), "+v"(W[t][1][p]));
            }
            const u32x4 words = {W[t][0][0], W[t][0][1], W[t][1][0], W[t][1][1]};
            pa[t] = __builtin_bit_cast(bf16x8, words);
        }

        // PV over this wave's key-half (kk = hn); lsum via ones-MFMA.
        // Vts reads safe: never a gload target; next overwrite after B1(kt+1).
        __builtin_amdgcn_s_setprio(1);
        accl[0] = __builtin_amdgcn_mfma_f32_16x16x32_bf16(ones, pa[0], accl[0], 0, 0, 0);
        accl[1] = __builtin_amdgcn_mfma_f32_16x16x32_bf16(ones, pa[1], accl[1], 0, 0, 0);
#pragma unroll
        for (int di = 0; di < 4; ++di) {
            const int d = 16 * di + c;
            const int kp = (hn * 32 + g * 8) ^ ((d >> 3) << 3);
            const bf16x8 vb = *(const bf16x8*)&Vts[d][kp];
            acc[0][di] = __builtin_amdgcn_mfma_f32_16x16x32_bf16(vb, pa[0], acc[0][di], 0, 0, 0);
            acc[1][di] = __builtin_amdgcn_mfma_f32_16x16x32_bf16(vb, pa[1], acc[1][di], 0, 0, 0);
        }
        __builtin_amdgcn_s_setprio(0);
    }

    // combine the two key-halves (hn=0 writes partials, hn=1 adds + finalizes)
    __syncthreads();
    float* sacc = SCs;                     // 256 slots x 8 f32x4 = 32KB
    float* sl   = (float*)&Ks[0];          // 256 slots x 2 f32
    const int slot = wq * 64 + l;
    if (hn == 0) {
#pragma unroll
        for (int t = 0; t < 2; ++t) {
            sl[slot * 2 + t] = accl[t][0];
#pragma unroll
            for (int di = 0; di < 4; ++di)
                *(f32x4*)&sacc[(slot * 8 + t * 4 + di) * 4] = acc[t][di];
        }
    }
    __syncthreads();
    if (hn == 1) {
#pragma unroll
        for (int t = 0; t < 2; ++t) {
            const float rl = 1.0f / (accl[t][0] + sl[slot * 2 + t]);
            const int q = qt * 128 + 64 * t + qrow;
#pragma unroll
            for (int di = 0; di < 4; ++di) {
                const f32x4 oa = acc[t][di] + *(const f32x4*)&sacc[(slot * 8 + t * 4 + di) * 4];
                bf16x4 o;
#pragma unroll
                for (int r = 0; r < 4; ++r) o[r] = (__bf16)(oa[r] * rl);
                *(bf16x4*)&outp[((size_t)(b * N_ + q)) * 512 + h * 64 + 16 * di + 4 * g] = o;
            }
        }
    }
}

// ---------------- launch ----------------
extern "C" void kernel_launch(void* const* d_in, const int* in_sizes, int n_in,
                              void* d_out, int out_size, void* d_ws, size_t ws_size,
                              hipStream_t stream) {
    (void)in_sizes; (void)n_in; (void)out_size; (void)ws_size;
    const float* x      = (const float*)d_in[0];
    const float* gamma  = (const float*)d_in[1];
    const float* dist   = (const float*)d_in[2];
    const float* ln1_w  = (const float*)d_in[3];
    const float* ln1_b  = (const float*)d_in[4];
    const float* qkv_w  = (const float*)d_in[5];
    const float* qkv_b  = (const float*)d_in[6];
    const float* proj_w = (const float*)d_in[7];
    const float* proj_b = (const float*)d_in[8];
    const float* ln2_w  = (const float*)d_in[9];
    const float* ln2_b  = (const float*)d_in[10];
    const float* fc1_w  = (const float*)d_in[11];
    const float* fc1_b  = (const float*)d_in[12];
    const float* fc2_w  = (const float*)d_in[13];
    const float* fc2_b  = (const float*)d_in[14];
    float* out = (float*)d_out;

    char* ws = (char*)d_ws;
    size_t off = 0;
    auto alloc = [&](size_t bytes) {
        void* p = ws + off; off = (off + bytes + 255) & ~(size_t)255; return p;
    };
    __bf16* qkv_wt  = (__bf16*)alloc((size_t)1536 * 512 * 2);
    __bf16* proj_wt = (__bf16*)alloc((size_t)512 * 512 * 2);
    __bf16* fc1_wt  = (__bf16*)alloc((size_t)2048 * 512 * 2);
    __bf16* fc2_wt  = (__bf16*)alloc((size_t)512 * 2048 * 2);
    __bf16* hbuf    = (__bf16*)alloc((size_t)BN_ * 512 * 2);
    __bf16* qkvbuf  = (__bf16*)alloc((size_t)BN_ * 1536 * 2);
    __bf16* attnbuf = (__bf16*)alloc((size_t)BN_ * 512 * 2);
    float*  x1buf   = (float*) alloc((size_t)BN_ * 512 * 4);
    __bf16* h2buf   = (__bf16*)alloc((size_t)BN_ * 512 * 2);
    __bf16* ffbuf   = (__bf16*)alloc((size_t)BN_ * 2048 * 2);

    prep_kernel<<<4096 + 3072, 256, 0, stream>>>(
        x, ln1_w, ln1_b, hbuf,
        qkv_w, qkv_wt, proj_w, proj_wt, fc1_w, fc1_wt, fc2_w, fc2_wt);
    gemm_bt<0,128,false><<<dim3(1536/128, BN_/128), 256, 0, stream>>>(
        hbuf, qkv_wt, qkv_b, nullptr, qkvbuf, nullptr, BN_, 1536, 512);
    attn_kernel<<<dim3(32, 8, 2), 512, 0, stream>>>(qkvbuf, dist, gamma, attnbuf);
    gemm_bt<2,64,false><<<dim3(512/64, BN_/128), 256, 0, stream>>>(
        attnbuf, proj_wt, proj_b, x, nullptr, x1buf, BN_, 512, 512);
    ln_kernel<<<BN_, 128, 0, stream>>>(x1buf, ln2_w, ln2_b, h2buf);
    gemm_bt<1,128,false><<<dim3(2048/128, BN_/128), 256, 0, stream>>>(
        h2buf, fc1_wt, fc1_b, nullptr, ffbuf, nullptr, BN_, 2048, 512);
    gemm_bt<2,64,false><<<dim3(512/64, BN_/128), 256, 0, stream>>>(
        ffbuf, fc2_wt, fc2_b, x1buf, nullptr, out, BN_, 512, 2048);
}

// Round 22
// 233.657 us; speedup vs baseline: 1.2060x; 1.2060x over previous
//
#include <hip/hip_runtime.h>
#include <math.h>

typedef __bf16 bf16x8 __attribute__((ext_vector_type(8)));
typedef __bf16 bf16x4 __attribute__((ext_vector_type(4)));
typedef float  f32x4  __attribute__((ext_vector_type(4)));
typedef unsigned int u32x4 __attribute__((ext_vector_type(4)));

#define B_   2
#define N_   4096
#define D_   512
#define H_   8
#define FF_  2048
#define BN_  (B_*N_)
static constexpr float SCALE_ = 0.04419417382415922f;  // 512^-0.5
static constexpr float LOG2E_ = 1.44269504088896341f;
static constexpr float SCALE_L2E_ = SCALE_ * LOG2E_;   // fold log2e into Q scale

#define GLOAD_LDS16(g, l) __builtin_amdgcn_global_load_lds( \
    (const __attribute__((address_space(1))) void*)(g),     \
    (__attribute__((address_space(3))) void*)(l), 16, 0, 0)

// ---------------- fused prep: ln1 (blocks 0..4095, 2 rows each) + all four ----------------
// weight transposes f32[R][C] -> bf16[C][R] (blocks 4096..7167, one 32x32 tile).
__global__ __launch_bounds__(256)
void prep_kernel(const float* __restrict__ x, const float* __restrict__ ln1_w,
                 const float* __restrict__ ln1_b, __bf16* __restrict__ hbuf,
                 const float* __restrict__ qkv_w,  __bf16* __restrict__ qkv_wt,
                 const float* __restrict__ proj_w, __bf16* __restrict__ proj_wt,
                 const float* __restrict__ fc1_w,  __bf16* __restrict__ fc1_wt,
                 const float* __restrict__ fc2_w,  __bf16* __restrict__ fc2_wt) {
    const int bid = blockIdx.x, tid = threadIdx.x;
    __shared__ float tile[32][33];
    __shared__ float ps[4][2];
    if (bid < 4096) {
        // ---- LayerNorm: two rows per block (group = tid>>7 of 128 threads) ----
        const int grp = tid >> 7, t = tid & 127;
        const int row = bid * 2 + grp;
        const float4 v = *(const float4*)&x[(size_t)row * 512 + t * 4];
        float s  = v.x + v.y + v.z + v.w;
        float sq = v.x*v.x + v.y*v.y + v.z*v.z + v.w*v.w;
#pragma unroll
        for (int mk = 1; mk < 64; mk <<= 1) { s += __shfl_xor(s, mk); sq += __shfl_xor(sq, mk); }
        if ((t & 63) == 0) { ps[tid >> 6][0] = s; ps[tid >> 6][1] = sq; }
        __syncthreads();
        s  = ps[grp * 2][0] + ps[grp * 2 + 1][0];
        sq = ps[grp * 2][1] + ps[grp * 2 + 1][1];
        const float mu  = s * (1.0f / 512.0f);
        const float var = sq * (1.0f / 512.0f) - mu * mu;
        const float rs  = rsqrtf(var + 1e-5f);
        const float4 wv = *(const float4*)&ln1_w[t * 4];
        const float4 bv = *(const float4*)&ln1_b[t * 4];
        bf16x4 o;
        o[0] = (__bf16)((v.x - mu) * rs * wv.x + bv.x);
        o[1] = (__bf16)((v.y - mu) * rs * wv.y + bv.y);
        o[2] = (__bf16)((v.z - mu) * rs * wv.z + bv.z);
        o[3] = (__bf16)((v.w - mu) * rs * wv.w + bv.w);
        *(bf16x4*)&hbuf[(size_t)row * 512 + t * 4] = o;
    } else {
        // ---- weight transpose tiles ----
        int idx = bid - 4096;
        const float* in; __bf16* out; int C, R, txc, tyr;
        if (idx < 768)       { in = qkv_w;  out = qkv_wt;  R = 512;  C = 1536;
                               txc = idx % 48; tyr = idx / 48; }
        else if (idx < 1024) { idx -= 768;  in = proj_w; out = proj_wt; R = 512;  C = 512;
                               txc = idx % 16; tyr = idx / 16; }
        else if (idx < 2048) { idx -= 1024; in = fc1_w;  out = fc1_wt;  R = 512;  C = 2048;
                               txc = idx % 64; tyr = idx / 64; }
        else                 { idx -= 2048; in = fc2_w;  out = fc2_wt;  R = 2048; C = 512;
                               txc = idx % 16; tyr = idx / 16; }
        const int c0 = txc * 32, r0 = tyr * 32;
        const int tx = tid & 31, ty = tid >> 5;   // (32,8)
#pragma unroll
        for (int i = 0; i < 4; ++i)
            tile[ty + 8*i][tx] = in[(size_t)(r0 + ty + 8*i) * C + c0 + tx];
        __syncthreads();
#pragma unroll
        for (int i = 0; i < 4; ++i)
            out[(size_t)(c0 + ty + 8*i) * R + r0 + tx] = (__bf16)tile[tx][ty + 8*i];
    }
}

// ---------------- LayerNorm f32 -> bf16, one row (512) per block of 128 ----------------
__global__ __launch_bounds__(128)
void ln_kernel(const float* __restrict__ x, const float* __restrict__ w,
               const float* __restrict__ b, __bf16* __restrict__ out) {
    const int row = blockIdx.x, t = threadIdx.x;
    const float4 v = *(const float4*)&x[(size_t)row * 512 + t * 4];
    float s  = v.x + v.y + v.z + v.w;
    float sq = v.x*v.x + v.y*v.y + v.z*v.z + v.w*v.w;
#pragma unroll
    for (int mk = 1; mk < 64; mk <<= 1) { s += __shfl_xor(s, mk); sq += __shfl_xor(sq, mk); }
    __shared__ float ps[2][2];
    if ((t & 63) == 0) { ps[t >> 6][0] = s; ps[t >> 6][1] = sq; }
    __syncthreads();
    s = ps[0][0] + ps[1][0]; sq = ps[0][1] + ps[1][1];
    const float mu  = s * (1.0f / 512.0f);
    const float var = sq * (1.0f / 512.0f) - mu * mu;
    const float rs  = rsqrtf(var + 1e-5f);
    const float4 wv = *(const float4*)&w[t * 4];
    const float4 bv = *(const float4*)&b[t * 4];
    bf16x4 o;
    o[0] = (__bf16)((v.x - mu) * rs * wv.x + bv.x);
    o[1] = (__bf16)((v.y - mu) * rs * wv.y + bv.y);
    o[2] = (__bf16)((v.z - mu) * rs * wv.z + bv.z);
    o[3] = (__bf16)((v.w - mu) * rs * wv.w + bv.w);
    *(bf16x4*)&out[(size_t)row * 512 + t * 4] = o;
}

// ---------------- bf16 GEMM, C = A[M,K] * Bt[N,K]^T, fused epilogues ----------------
// EPI 0: +bias -> bf16 | EPI 1: +bias, exact gelu -> bf16 | EPI 2: +bias +resid(f32) -> f32
// Epilogue is LDS-transposed + vectorized (r14 win: 64 scalar VMEM -> 8/16 vector).
template<int EPI, int BNT, bool DBUF>
__global__ __launch_bounds__(256, 4)
void gemm_bt(const __bf16* __restrict__ A, const __bf16* __restrict__ Bt,
             const float* __restrict__ bias, const float* __restrict__ resid,
             __bf16* __restrict__ outb, float* __restrict__ outf,
             int M, int N, int K) {
    constexpr int NI = BNT / 32;                  // n-frags per wave (4 or 2)
    constexpr int NB = DBUF ? 2 : 1;
    __shared__ __align__(16) __bf16 As[NB][128 * 64];
    __shared__ __align__(16) __bf16 Bs[NB][BNT * 64];
    const int tid = threadIdx.x;
    const int w = tid >> 6, l = tid & 63;
    const int g = l >> 4, c = l & 15;
    const int m0 = blockIdx.y * 128, n0 = blockIdx.x * BNT;
    const int wm = (w >> 1) * 64, wn = (w & 1) * (BNT / 2);
    f32x4 acc[4][NI] = {};

    auto stage = [&](int kt, int buf) {
#pragma unroll
        for (int i = 0; i < 4; ++i) {             // A tile: 128x64
            const int cb = (i * 4 + w) * 64;      // wave-uniform chunk base
            const int chunk = cb + l;
            const int row = chunk >> 3, c8 = chunk & 7;
            GLOAD_LDS16(A + (size_t)(m0 + row) * K + kt + c8 * 8, As[buf] + cb * 8);
        }
#pragma unroll
        for (int i = 0; i < BNT / 32; ++i) {      // B tile: BNTx64
            const int cb = (i * 4 + w) * 64;
            const int chunk = cb + l;
            const int row = chunk >> 3, c8 = chunk & 7;
            GLOAD_LDS16(Bt + (size_t)(n0 + row) * K + kt + c8 * 8, Bs[buf] + cb * 8);
        }
    };
    auto compute = [&](int buf) {
#pragma unroll
        for (int kk = 0; kk < 2; ++kk) {
            bf16x8 av[4], bv[NI];
#pragma unroll
            for (int mi = 0; mi < 4; ++mi)
                av[mi] = *(const bf16x8*)&As[buf][(wm + mi * 16 + c) * 64 + kk * 32 + g * 8];
#pragma unroll
            for (int ni = 0; ni < NI; ++ni)
                bv[ni] = *(const bf16x8*)&Bs[buf][(wn + ni * 16 + c) * 64 + kk * 32 + g * 8];
#pragma unroll
            for (int mi = 0; mi < 4; ++mi)
#pragma unroll
                for (int ni = 0; ni < NI; ++ni)
                    acc[mi][ni] = __builtin_amdgcn_mfma_f32_16x16x32_bf16(
                        av[mi], bv[ni], acc[mi][ni], 0, 0, 0);
        }
    };

    if constexpr (DBUF) {
        stage(0, 0);
        const int T = K / 64;
        for (int t = 0; t < T; ++t) {
            const int cur = t & 1;
            __syncthreads();
            if (t + 1 < T) stage((t + 1) * 64, cur ^ 1);
            compute(cur);
        }
    } else {
        for (int kt = 0; kt < K; kt += 64) {
            __syncthreads();
            stage(kt, 0);
            __syncthreads();
            compute(0);
        }
    }

    // ---- vectorized epilogue (wave-local LDS transpose) ----
    __syncthreads();   // all waves done reading As/Bs before we overwrite As
    if constexpr (EPI == 2) {
        // f32 path: per-wave [16][NI*16 + 4] f32 patch in As
        constexpr int LDW = NI * 16 + 4;
        float* ep = (float*)&As[0][0] + w * (16 * LDW);
#pragma unroll
        for (int mi = 0; mi < 4; ++mi) {
#pragma unroll
            for (int ni = 0; ni < NI; ++ni)
#pragma unroll
                for (int r = 0; r < 4; ++r)
                    ep[(g * 4 + r) * LDW + ni * 16 + c] =
                        acc[mi][ni][r] + bias[n0 + wn + ni * 16 + c];
#pragma unroll
            for (int rnd = 0; rnd < NI; ++rnd) {          // 16*NI*16 f32 / (64*4)
                const int idx = rnd * 64 + l;
                const int rr = idx >> 3, cc = idx & 7;
                const f32x4 vv = *(const f32x4*)&ep[rr * LDW + cc * 4];
                const size_t oidx = (size_t)(m0 + wm + mi * 16 + rr) * N + n0 + wn + cc * 4;
                const f32x4 rv = *(const f32x4*)&resid[oidx];
                *(f32x4*)&outf[oidx] = vv + rv;
            }
        }
    } else {
        // bf16 path: per-wave [16][NI*16 + 8] bf16 patch in As
        constexpr int LDW = NI * 16 + 8;
        __bf16* ep = &As[0][0] + w * (16 * LDW);
#pragma unroll
        for (int mi = 0; mi < 4; ++mi) {
#pragma unroll
            for (int ni = 0; ni < NI; ++ni)
#pragma unroll
                for (int r = 0; r < 4; ++r) {
                    float v = acc[mi][ni][r] + bias[n0 + wn + ni * 16 + c];
                    if constexpr (EPI == 1)
                        v = 0.5f * v * (1.0f + erff(v * 0.70710678118654752f));
                    ep[(g * 4 + r) * LDW + ni * 16 + c] = (__bf16)v;
                }
#pragma unroll
            for (int rnd = 0; rnd < NI / 2; ++rnd) {      // 16*NI*16 bf16 / (64*8)
                const int idx = rnd * 64 + l;
                const int rr = idx >> 3, cc = idx & 7;
                const bf16x8 vv = *(const bf16x8*)&ep[rr * LDW + cc * 8];
                const size_t oidx = (size_t)(m0 + wm + mi * 16 + rr) * N + n0 + wn + cc * 8;
                *(bf16x8*)&outb[oidx] = vv;
            }
        }
    }
}

// ---------------- flash attention: 8 waves, ni-split key halves (r20, final) ----------------
// Two barriers/iter: B1 full drain (K/V/dist landed, PV done), B2 lgkm+barrier
// after ALL LDS reads hoisted (Cin from DPsF + kf from Ks) -> Ks AND DPsF free
// at B2, so both prefetches issue there with full-iteration windows. dist flows
// through the coalesced gload_lds path (r1/r21 proved direct-to-reg scatter
// loses: +22MB FETCH, VALUBusy collapse). lsum via ones-MFMA; setprio wraps
// MFMA clusters; fused finalize with cross-wave key-half combine through LDS.
__global__ __launch_bounds__(512, 4)
void attn_kernel(const __bf16* __restrict__ qkv, const float* __restrict__ dist,
                 const float* __restrict__ gamma, __bf16* __restrict__ outp) {
    __shared__ __align__(16) __bf16 Ks [64 * 64];      // K tile, linear + XOR swizzle
    __shared__ __align__(16) __bf16 Vts[64][72];       // V transposed, k XOR-swizzled
    __shared__ __align__(16) float  DPsF[128 * 64];    // dist f32, single buffer
    const int tid = threadIdx.x;
    const int w = tid >> 6, l = tid & 63;
    const int g = l >> 4, c = l & 15;
    const int wq = w & 3, hn = w >> 2;              // q-row group, key-half
    const int qt = blockIdx.x, h = blockIdx.y;
    const int b = blockIdx.z;
    const float gbl = gamma[b] * LOG2E_;
    const size_t tok0 = (size_t)b * N_;
    const int qrow = 16 * wq + c;                   // lane's local q row (group 0)
    const int wub = tid & 448;                      // w*64, wave-uniform lds chunk base
    const int srow = tid >> 3;                      // staging row (0..63), K/V
    const int sd0  = (tid & 7) * 8;                 // staging d-offset
    const int cswz = ((tid & 7) ^ (srow & 7)) * 8;  // K source pre-swizzle col
    const int swz  = (c & 7) << 3;                  // LDS read swizzle (bf16)

    // Q fragments for both t-groups, pre-scaled by SCALE*log2e
    bf16x8 qf[2][2];
#pragma unroll
    for (int t = 0; t < 2; ++t) {
        const size_t qbase = (tok0 + qt * 128 + 64 * t + qrow) * 1536 + h * 64;
#pragma unroll
        for (int kk = 0; kk < 2; ++kk) {
            const bf16x8 qv = *(const bf16x8*)&qkv[qbase + kk * 32 + g * 8];
#pragma unroll
            for (int j = 0; j < 8; ++j) qf[t][kk][j] = (__bf16)((float)qv[j] * SCALE_L2E_);
        }
    }
    bf16x8 ones;
#pragma unroll
    for (int j = 0; j < 8; ++j) ones[j] = (__bf16)1.0f;

    f32x4 acc[2][4] = {};   // key-half partial: Onum[q=64t+qrow][d=16di+4g+r]
    f32x4 accl[2] = {};     // key-half partial softmax denominator
    bf16x8 vreg;

    // running global pointers (strength-reduced: advance by constant stride)
    const size_t kvstep = (size_t)64 * 1536;
    const __bf16* gk = qkv + 512  + (tok0 + srow) * 1536 + h * 64 + cswz;
    const __bf16* gv = qkv + 1024 + (tok0 + srow) * 1536 + h * 64 + sd0;
    // dist f32 staging: thread -> (row = i*32 + (tid>>4), chunk ccol = tid&15),
    // source chunk pre-swizzled by row&7 (= (tid>>4)&7, i-independent).
    const int drow = tid >> 4;
    const float* gd = dist + (size_t)(qt * 128 + drow) * N_
                    + ((tid & 15) ^ (drow & 7)) * 4;

    auto issue_k = [&]() {
        GLOAD_LDS16(gk, Ks + wub * 8);
        gk += kvstep;
    };
    auto issue_d = [&]() {
#pragma unroll
        for (int i = 0; i < 4; ++i)
            GLOAD_LDS16(gd + (size_t)i * 32 * N_, DPsF + i * 2048 + wub * 4);
        gd += 64;
    };
    auto issue_v = [&]() {
        vreg = *(const bf16x8*)gv;
        gv += kvstep;
    };
    auto write_vts = [&]() {    // scalar transpose: vreg -> Vts
        const int kp = srow ^ sd0;   // sd0 = (sd0>>3)<<3 here
#pragma unroll
        for (int j = 0; j < 8; ++j) Vts[sd0 + j][kp] = vreg[j];
    };

    const int ktend = N_ / 64;                      // 64 tiles, all keys
    issue_k();
    issue_v();
    issue_d();

    for (int kt = 0; kt < ktend; ++kt) {
        __syncthreads();     // B1: full drain -- K/V/dist(kt) landed, PV(kt-1) done
        write_vts();
        if (kt + 1 < ktend) issue_v();   // vreg dead after write_vts
        __builtin_amdgcn_sched_barrier(0);

        // hoisted LDS reads: Cin (dist) AND kf (K) -> registers.
        f32x4 cin0[2], cin1[2];          // [nii]: rows qrow, 64+qrow
        bf16x8 kf[2][2];                 // [nii][kk]
#pragma unroll
        for (int nii = 0; nii < 2; ++nii) {
            const int ni = 2 * hn + nii;
            const int dcol = (16 * ni + 4 * g) ^ ((c & 7) << 2);
            const f32x4 dd0 = *(const f32x4*)&DPsF[(qrow << 6) + dcol];
            const f32x4 dd1 = *(const f32x4*)&DPsF[((64 + qrow) << 6) + dcol];
#pragma unroll
            for (int r = 0; r < 4; ++r) {
                cin0[nii][r] = -gbl * dd0[r];
                cin1[nii][r] = -gbl * dd1[r];
            }
#pragma unroll
            for (int kk = 0; kk < 2; ++kk)
                kf[nii][kk] = *(const bf16x8*)
                    &Ks[((16 * ni + c) << 6) + ((kk * 32 + g * 8) ^ swz)];
        }
        __builtin_amdgcn_sched_barrier(0);
        // B2: ALL LDS reads of this iter done (Cin+kf); own Vts writes drained
        // and made visible to the other waves. Ks and DPsF both free now.
        asm volatile("s_waitcnt lgkmcnt(0)\n\ts_barrier" ::: "memory");
        __builtin_amdgcn_sched_barrier(0);
        if (kt + 1 < ktend) {    // both prefetches fly across the whole iteration
            issue_k();
            issue_d();
        }

        // QK^T from registers, Cin = -gbl*dd preloaded
        uint32_t W[2][2][2];
#pragma unroll
        for (int nii = 0; nii < 2; ++nii) {
            f32x4 s0 = cin0[nii], s1 = cin1[nii];
            __builtin_amdgcn_s_setprio(1);
#pragma unroll
            for (int kk = 0; kk < 2; ++kk) {
                s0 = __builtin_amdgcn_mfma_f32_16x16x32_bf16(kf[nii][kk], qf[0][kk], s0, 0, 0, 0);
                s1 = __builtin_amdgcn_mfma_f32_16x16x32_bf16(kf[nii][kk], qf[1][kk], s1, 0, 0, 0);
            }
            __builtin_amdgcn_s_setprio(0);
#pragma unroll
            for (int t = 0; t < 2; ++t) {
                const f32x4 sv = (t == 0) ? s0 : s1;
                float pv0, pv1, pv2, pv3;
                pv0 = __builtin_amdgcn_exp2f(sv[0]);
                pv1 = __builtin_amdgcn_exp2f(sv[1]);
                pv2 = __builtin_amdgcn_exp2f(sv[2]);
                pv3 = __builtin_amdgcn_exp2f(sv[3]);
                asm("v_cvt_pk_bf16_f32 %0, %1, %2" : "=v"(W[t][nii][0]) : "v"(pv0), "v"(pv1));
                asm("v_cvt_pk_bf16_f32 %0, %1, %2" : "=v"(W[t][nii][1]) : "v"(pv2), "v"(pv3));
            }
        }
        // P-word exchange within the half: (W[nii=0],W[nii=1]) -> pa[kk=hn]
        bf16x8 pa[2];
#pragma unroll
        for (int t = 0; t < 2; ++t) {
#pragma unroll
            for (int p = 0; p < 2; ++p) {
                asm("v_permlane32_swap_b32 %0, %1"
                    : "+v"(W[t][0][p]), "+v"(W[t][1][p]));
                asm("v_permlane16_swap_b32 %0, %1"
                    : "+v"(W[t][0][p]), "+v"(W[t][1][p]));
            }
            const u32x4 words = {W[t][0][0], W[t][0][1], W[t][1][0], W[t][1][1]};
            pa[t] = __builtin_bit_cast(bf16x8, words);
        }

        // PV over this wave's key-half (kk = hn); lsum via ones-MFMA.
        // Vts reads are safe: Vts is never a gload target and its next
        // overwrite is after B1(kt+1)'s full drain.
        __builtin_amdgcn_s_setprio(1);
        accl[0] = __builtin_amdgcn_mfma_f32_16x16x32_bf16(ones, pa[0], accl[0], 0, 0, 0);
        accl[1] = __builtin_amdgcn_mfma_f32_16x16x32_bf16(ones, pa[1], accl[1], 0, 0, 0);
#pragma unroll
        for (int di = 0; di < 4; ++di) {
            const int d = 16 * di + c;
            const int kp = (hn * 32 + g * 8) ^ ((d >> 3) << 3);
            const bf16x8 vb = *(const bf16x8*)&Vts[d][kp];
            acc[0][di] = __builtin_amdgcn_mfma_f32_16x16x32_bf16(vb, pa[0], acc[0][di], 0, 0, 0);
            acc[1][di] = __builtin_amdgcn_mfma_f32_16x16x32_bf16(vb, pa[1], acc[1][di], 0, 0, 0);
        }
        __builtin_amdgcn_s_setprio(0);
    }

    // combine the two key-halves (hn=0 writes partials, hn=1 adds + finalizes)
    __syncthreads();
    float* sacc = DPsF;                    // 256 slots x 8 f32x4 = 32KB
    float* sl   = (float*)&Ks[0];          // 256 slots x 2 f32
    const int slot = wq * 64 + l;
    if (hn == 0) {
#pragma unroll
        for (int t = 0; t < 2; ++t) {
            sl[slot * 2 + t] = accl[t][0];
#pragma unroll
            for (int di = 0; di < 4; ++di)
                *(f32x4*)&sacc[(slot * 8 + t * 4 + di) * 4] = acc[t][di];
        }
    }
    __syncthreads();
    if (hn == 1) {
#pragma unroll
        for (int t = 0; t < 2; ++t) {
            const float rl = 1.0f / (accl[t][0] + sl[slot * 2 + t]);
            const int q = qt * 128 + 64 * t + qrow;
#pragma unroll
            for (int di = 0; di < 4; ++di) {
                const f32x4 oa = acc[t][di] + *(const f32x4*)&sacc[(slot * 8 + t * 4 + di) * 4];
                bf16x4 o;
#pragma unroll
                for (int r = 0; r < 4; ++r) o[r] = (__bf16)(oa[r] * rl);
                *(bf16x4*)&outp[((size_t)(b * N_ + q)) * 512 + h * 64 + 16 * di + 4 * g] = o;
            }
        }
    }
}

// ---------------- launch ----------------
extern "C" void kernel_launch(void* const* d_in, const int* in_sizes, int n_in,
                              void* d_out, int out_size, void* d_ws, size_t ws_size,
                              hipStream_t stream) {
    (void)in_sizes; (void)n_in; (void)out_size; (void)ws_size;
    const float* x      = (const float*)d_in[0];
    const float* gamma  = (const float*)d_in[1];
    const float* dist   = (const float*)d_in[2];
    const float* ln1_w  = (const float*)d_in[3];
    const float* ln1_b  = (const float*)d_in[4];
    const float* qkv_w  = (const float*)d_in[5];
    const float* qkv_b  = (const float*)d_in[6];
    const float* proj_w = (const float*)d_in[7];
    const float* proj_b = (const float*)d_in[8];
    const float* ln2_w  = (const float*)d_in[9];
    const float* ln2_b  = (const float*)d_in[10];
    const float* fc1_w  = (const float*)d_in[11];
    const float* fc1_b  = (const float*)d_in[12];
    const float* fc2_w  = (const float*)d_in[13];
    const float* fc2_b  = (const float*)d_in[14];
    float* out = (float*)d_out;

    char* ws = (char*)d_ws;
    size_t off = 0;
    auto alloc = [&](size_t bytes) {
        void* p = ws + off; off = (off + bytes + 255) & ~(size_t)255; return p;
    };
    __bf16* qkv_wt  = (__bf16*)alloc((size_t)1536 * 512 * 2);
    __bf16* proj_wt = (__bf16*)alloc((size_t)512 * 512 * 2);
    __bf16* fc1_wt  = (__bf16*)alloc((size_t)2048 * 512 * 2);
    __bf16* fc2_wt  = (__bf16*)alloc((size_t)512 * 2048 * 2);
    __bf16* hbuf    = (__bf16*)alloc((size_t)BN_ * 512 * 2);
    __bf16* qkvbuf  = (__bf16*)alloc((size_t)BN_ * 1536 * 2);
    __bf16* attnbuf = (__bf16*)alloc((size_t)BN_ * 512 * 2);
    float*  x1buf   = (float*) alloc((size_t)BN_ * 512 * 4);
    __bf16* h2buf   = (__bf16*)alloc((size_t)BN_ * 512 * 2);
    __bf16* ffbuf   = (__bf16*)alloc((size_t)BN_ * 2048 * 2);

    prep_kernel<<<4096 + 3072, 256, 0, stream>>>(
        x, ln1_w, ln1_b, hbuf,
        qkv_w, qkv_wt, proj_w, proj_wt, fc1_w, fc1_wt, fc2_w, fc2_wt);
    gemm_bt<0,128,false><<<dim3(1536/128, BN_/128), 256, 0, stream>>>(
        hbuf, qkv_wt, qkv_b, nullptr, qkvbuf, nullptr, BN_, 1536, 512);
    attn_kernel<<<dim3(32, 8, 2), 512, 0, stream>>>(qkvbuf, dist, gamma, attnbuf);
    gemm_bt<2,64,false><<<dim3(512/64, BN_/128), 256, 0, stream>>>(
        attnbuf, proj_wt, proj_b, x, nullptr, x1buf, BN_, 512, 512);
    ln_kernel<<<BN_, 128, 0, stream>>>(x1buf, ln2_w, ln2_b, h2buf);
    gemm_bt<1,128,false><<<dim3(2048/128, BN_/128), 256, 0, stream>>>(
        h2buf, fc1_wt, fc1_b, nullptr, ffbuf, nullptr, BN_, 2048, 512);
    gemm_bt<2,64,false><<<dim3(512/64, BN_/128), 256, 0, stream>>>(
        ffbuf, fc2_wt, fc2_b, x1buf, nullptr, out, BN_, 512, 2048);
}